// Round 12
// baseline (156.583 us; speedup 1.0000x reference)
//
#include <hip/hip_runtime.h>

typedef __bf16 bf16x8 __attribute__((ext_vector_type(8)));
typedef float f32x4 __attribute__((ext_vector_type(4)));

#define DEV __device__ __forceinline__

DEV unsigned short f2bf(float f) {
  union { float f; unsigned u; } x; x.f = f;
  unsigned r = x.u + 0x7FFFu + ((x.u >> 16) & 1u);  // RNE
  return (unsigned short)(r >> 16);
}
DEV float bf2f(unsigned short h) {
  union { unsigned u; float f; } x; x.u = ((unsigned)h) << 16;
  return x.f;
}
DEV unsigned short bfc(float f) {  // hw cvt (RNE)
  union { __bf16 b; unsigned short u; } c; c.b = (__bf16)f; return c.u;
}

typedef __attribute__((address_space(3))) void* lds_vp;
typedef const __attribute__((address_space(1))) void* gbl_vp;
DEV void load_lds16(const unsigned short* gp, void* lp) {
  __builtin_amdgcn_global_load_lds((gbl_vp)(const void*)gp, (lds_vp)lp, 16, 0, 0);
}

// ---- fused ingest (inputs f32): convert x/rel/bo, transpose Wq|Wkv|Wo -----
__global__ __launch_bounds__(256)
void prep_k(const float* __restrict__ x, const float* __restrict__ rel,
            const float* __restrict__ bo, const float* __restrict__ Wq,
            const float* __restrict__ Wkv, const float* __restrict__ Wo,
            unsigned short* __restrict__ xb, unsigned short* __restrict__ relb,
            unsigned short* __restrict__ bob, unsigned short* __restrict__ WqkvT,
            unsigned short* __restrict__ WoT) {
  __shared__ unsigned short tile[32][33];
  const int bid = blockIdx.x, tid = threadIdx.x;
  if (bid < 2114) {
    const float* src; unsigned short* dst; long base; long n;
    if (bid < 2048)      { src = x;   dst = xb;   base = (long)bid * 1024;          n = 2097152; }
    else if (bid < 2113) { src = rel; dst = relb; base = (long)(bid - 2048) * 1024; n = 65600; }
    else                 { src = bo;  dst = bob;  base = 0;                          n = 1024; }
    long i = base + tid * 4;
    if (i < n) {
      float4 v = *(const float4*)&src[i];
      unsigned long long u = (unsigned long long)f2bf(v.x)
                           | ((unsigned long long)f2bf(v.y) << 16)
                           | ((unsigned long long)f2bf(v.z) << 32)
                           | ((unsigned long long)f2bf(v.w) << 48);
      *(unsigned long long*)&dst[i] = u;
    }
  } else {
    int id = bid - 2114;
    const float* src; unsigned short* dst; const int R = 1024; int C, txt, tyt;
    if (id < 1024)      { src = Wq;  dst = WqkvT;           C = 1024; txt = id & 31; tyt = id >> 5; }
    else if (id < 3072) { int l = id - 1024; src = Wkv; dst = WqkvT + 1048576; C = 2048; txt = l & 63; tyt = l >> 6; }
    else                { int l = id - 3072; src = Wo;  dst = WoT;             C = 1024; txt = l & 31; tyt = l >> 5; }
    int c0 = txt * 32, r0 = tyt * 32;
    int tx = tid & 31, ty = tid >> 5;
    #pragma unroll
    for (int i = 0; i < 4; ++i)
      tile[ty + i * 8][tx] = f2bf(src[(size_t)(r0 + ty + i * 8) * C + c0 + tx]);
    __syncthreads();
    #pragma unroll
    for (int i = 0; i < 4; ++i)
      dst[(size_t)(c0 + ty + i * 8) * R + r0 + tx] = tile[tx][ty + i * 8];
  }
}

// ---- XOR-8 swizzled staging/read for 64-short-row LDS tiles ---------------
DEV void stage16(const unsigned short* gbase, size_t gstride,
                 unsigned short* lbase, int r0, int lane) {
  #pragma unroll
  for (int t = 0; t < 2; ++t) {
    int r = r0 + t * 8 + (lane >> 3);
    int lc = (lane & 7) ^ (r & 7);
    load_lds16(&gbase[(size_t)r * gstride + lc * 8], &lbase[(size_t)(r0 + t * 8) * 64]);
  }
}
DEV bf16x8 read_swz(const unsigned short* buf, int row, int lc) {
  int pc = lc ^ (row & 7);
  return *(const bf16x8*)&buf[row * 64 + pc * 8];
}

// ---------------- GEMM qkv = x @ WqkvT^T — 64x128 tiles, BK=128 ------------
// R11-proven: lo/hi K-halves, barriers halved, 768 blocks = 3/CU balanced.
__global__ __launch_bounds__(256)
void gemm_qkv(const unsigned short* __restrict__ A,
              const unsigned short* __restrict__ Bt,
              unsigned short* __restrict__ o0,   // q [b,h,n,d] *0.125
              unsigned short* __restrict__ o1,   // k [b,h,n,d]
              unsigned short* __restrict__ o2) { // vT [b,h,d,n]
  union UA {
    unsigned short As2[2][64 * 64];   // lo/hi K-halves
    unsigned short tb[64][68];        // epilogue only (A dead then)
  };
  __shared__ __align__(16) UA u;
  __shared__ __align__(16) unsigned short Bs2[2][128 * 64];
  const int tid  = threadIdx.x;
  const int lane = tid & 63, wave = tid >> 6;
  const int q15  = lane & 15, quad = lane >> 4;
  const int wr = wave >> 1, wc = wave & 1;
  const int m0 = blockIdx.y * 64, n0 = blockIdx.x * 128;
  const int K = 1024;

  f32x4 acc[2][4] = {};
  for (int k0 = 0; k0 < K; k0 += 128) {
    __syncthreads();
    stage16(&A[(size_t)m0 * K + k0], K, u.As2[0], wave * 16, lane);
    stage16(&A[(size_t)m0 * K + k0 + 64], K, u.As2[1], wave * 16, lane);
    stage16(&Bt[(size_t)n0 * K + k0], K, Bs2[0], wave * 32, lane);
    stage16(&Bt[(size_t)n0 * K + k0], K, Bs2[0], wave * 32 + 16, lane);
    stage16(&Bt[(size_t)n0 * K + k0 + 64], K, Bs2[1], wave * 32, lane);
    stage16(&Bt[(size_t)n0 * K + k0 + 64], K, Bs2[1], wave * 32 + 16, lane);
    __syncthreads();
    #pragma unroll
    for (int ks = 0; ks < 4; ++ks) {
      const int hf = ks >> 1, kk = ks & 1;
      bf16x8 af[2], bfr[4];
      #pragma unroll
      for (int i = 0; i < 2; ++i)
        af[i] = read_swz(u.As2[hf], wr * 32 + i * 16 + q15, kk * 4 + quad);
      #pragma unroll
      for (int j = 0; j < 4; ++j)
        bfr[j] = read_swz(Bs2[hf], wc * 64 + j * 16 + q15, kk * 4 + quad);
      #pragma unroll
      for (int i = 0; i < 2; ++i)
        #pragma unroll
        for (int j = 0; j < 4; ++j)
          acc[i][j] = __builtin_amdgcn_mfma_f32_16x16x32_bf16(af[i], bfr[j], acc[i][j], 0, 0, 0);
    }
  }

  const int b = m0 >> 10, nn0 = m0 & 1023;
  if (n0 < 2048) {
    #pragma unroll
    for (int i = 0; i < 2; ++i)
      #pragma unroll
      for (int j = 0; j < 4; ++j)
        #pragma unroll
        for (int r = 0; r < 4; ++r) {
          int row = m0 + wr * 32 + i * 16 + quad * 4 + r;
          int col = n0 + wc * 64 + j * 16 + q15;
          float v = acc[i][j][r];
          int nn = row & 1023;
          unsigned short* dst; int c = col; float sc = 1.f;
          if (col < 1024) { dst = o0; sc = 0.125f; }
          else            { dst = o1; c = col - 1024; }
          int h = c >> 6, dd = c & 63;
          dst[((size_t)((row >> 10) * 16 + h) * 1024 + nn) * 64 + dd] = f2bf(v * sc);
        }
  } else {
    const int hp = (n0 - 2048) >> 6;
    #pragma unroll
    for (int hh = 0; hh < 2; ++hh) {
      __syncthreads();
      if (wc == hh) {
        #pragma unroll
        for (int i = 0; i < 2; ++i)
          #pragma unroll
          for (int j = 0; j < 4; ++j)
            #pragma unroll
            for (int r = 0; r < 4; ++r)
              u.tb[wr * 32 + i * 16 + quad * 4 + r][j * 16 + q15] = f2bf(acc[i][j][r]);
      }
      __syncthreads();
      const int bh = b * 16 + hp + hh;
      const int d = tid >> 2, nb = (tid & 3) * 16;
      #pragma unroll
      for (int s = 0; s < 2; ++s) {
        int n = nb + s * 8;
        union { uint4 v; unsigned short us[8]; } t;
        #pragma unroll
        for (int e = 0; e < 8; ++e) t.us[e] = u.tb[n + e][d];
        *(uint4*)&o2[((size_t)bh * 64 + d) * 1024 + nn0 + n] = t.v;
      }
    }
  }
}

// ---------------- flash attention: SWAPPED operands, 8-wave j-split --------
// R12: R8 structure + jt-loop ROTATION for blocks with blockIdx.y >= 8.
// Theory: per-CU pipe cycles SUM to runtime (LDS 43% + VALU 28% + MFMA 13%)
// because all 16 resident waves (2 blocks) are phase-locked — same phase,
// same pipe, serialized. Co-resident pair is (bid, bid+256) = blockIdx.y
// and blockIdx.y+8; rotating the second block's jt order by 4 de-phases the
// pair so one block's LDS phase overlaps the other's VALU/MFMA phase.
// Order-independent sums (R1 proved reordering passes); zero cost.
__global__ __launch_bounds__(512)
void flash_attn(const unsigned short* __restrict__ q_ws,   // pre-scaled .125
                const unsigned short* __restrict__ k_ws,
                const unsigned short* __restrict__ vt_ws,  // [bh][64][1024]
                const unsigned short* __restrict__ rel,    // [1025][64]
                unsigned short* __restrict__ ao) {         // [2048][1024]
  __shared__ __align__(16) unsigned short Kbuf[2][64 * 64];   // [j-half]
  __shared__ __align__(16) unsigned short Vbuf[2][64 * 64];   // [j-half]
  __shared__ __align__(16) unsigned short P_lds[8][16 * 64];  // XOR-8 16B slots
  union TXu {
    unsigned short T[8][16][84];  // bf16 band, rows = i, cols = band-c
    float bnc[4][65][17];         // epilogue o/l exchange (B-half -> A-half)
  };
  __shared__ __align__(16) TXu tx;

  const int tid  = threadIdx.x;
  const int lane = tid & 63, w = tid >> 6;
  const int q15  = lane & 15, quad = lane >> 4;
  const int wr4  = w & 3, jh = w >> 2;
  const int bh = blockIdx.x;
  const int ib = blockIdx.y * 64 + wr4 * 16;
  const int skew = (blockIdx.y >> 3) * 4;   // de-phase co-resident block pair

  const unsigned short* qp = q_ws  + (size_t)bh * 1024 * 64;
  const unsigned short* kp = k_ws  + (size_t)bh * 1024 * 64;
  const unsigned short* tp = vt_ws + (size_t)bh * 64 * 1024;

  unsigned short* Kb = &Kbuf[jh][0];
  unsigned short* Vb = &Vbuf[jh][0];
  unsigned short* Trow = &tx.T[w][q15][0];          // this lane's i-row band
  unsigned short* Prow = &P_lds[w][q15 * 64];       // this lane's i-row P

  bf16x8 aq[2];
  #pragma unroll
  for (int ks = 0; ks < 2; ++ks)
    aq[ks] = *(const bf16x8*)&qp[(size_t)(ib + q15) * 64 + ks * 32 + quad * 8];

  f32x4 o[4] = {};          // o[db][r]: out[d = db*16+quad*4+r][i = q15]
  float l_acc = 0.f;        // row-sum for i = ib + q15 (partial over quads)

  for (int t = 0; t < 8; ++t) {
    const int jt = (t + skew) & 7;
    const int j0 = jh * 512 + jt * 64;
    __syncthreads();  // prev-iter K/V reads done; buffers free
    stage16(kp + (size_t)j0 * 64, 64, Kb, wr4 * 16, lane);
    stage16(tp + j0, 1024, Vb, wr4 * 16, lane);

    // T-phase (swapped: A=rel, B=q): out[trow-row][i-col]. Independent of
    // K/V buffers — overlaps staging latency.
    int tb = ib - j0 + 512 - 63;
    f32x4 accT[5] = {};
    __builtin_amdgcn_s_setprio(1);
    #pragma unroll
    for (int ks = 0; ks < 2; ++ks)
      #pragma unroll
      for (int ub = 0; ub < 5; ++ub) {
        int trow = tb + ub * 16 + q15;
        trow = trow < 0 ? 0 : (trow > 1024 ? 1024 : trow);
        bf16x8 br = *(const bf16x8*)&rel[(size_t)trow * 64 + ks * 32 + quad * 8];
        accT[ub] = __builtin_amdgcn_mfma_f32_16x16x32_bf16(br, aq[ks], accT[ub], 0, 0, 0);
      }
    __builtin_amdgcn_s_setprio(0);
    // lane holds T[trow = tb+ub*16+quad*4+r][i=q15] -> store T[i][c],
    // c = ub*16+quad*4+r: 4 contiguous per ub -> packed b64 writes.
    #pragma unroll
    for (int ub = 0; ub < 5; ++ub) {
      uint2 tw;
      tw.x = (unsigned)bfc(accT[ub][0]) | ((unsigned)bfc(accT[ub][1]) << 16);
      tw.y = (unsigned)bfc(accT[ub][2]) | ((unsigned)bfc(accT[ub][3]) << 16);
      *(uint2*)&Trow[ub * 16 + quad * 4] = tw;
    }

    __syncthreads();  // staging landed (vmcnt drained before barrier)

    // S' = mfma(A=K, B=Q): lane holds S[j = j0+cb*16+quad*4+r][i = ib+q15]
    f32x4 accS[4] = {};
    __builtin_amdgcn_s_setprio(1);
    #pragma unroll
    for (int ks = 0; ks < 2; ++ks)
      #pragma unroll
      for (int cb = 0; cb < 4; ++cb) {
        bf16x8 bk = read_swz(Kb, cb * 16 + q15, ks * 4 + quad);
        accS[cb] = __builtin_amdgcn_mfma_f32_16x16x32_bf16(bk, aq[ks], accS[cb], 0, 0, 0);
      }
    __builtin_amdgcn_s_setprio(0);

    // softmax: i fixed per lane; T gather is T[i][63 + q15 - j_local]
    #pragma unroll
    for (int cb = 0; cb < 4; ++cb) {
      float p[4];
      #pragma unroll
      for (int r = 0; r < 4; ++r) {
        int jl = cb * 16 + quad * 4 + r;
        float s = accS[cb][r] + bf2f(Trow[63 + q15 - jl]);
        p[r] = exp2f(fmaf(s, 1.44269504f, -64.f));
        l_acc += p[r];
      }
      uint2 pw;
      pw.x = (unsigned)bfc(p[0]) | ((unsigned)bfc(p[1]) << 16);
      pw.y = (unsigned)bfc(p[2]) | ((unsigned)bfc(p[3]) << 16);
      // j = cb*16+quad*4+r; 16B slot = cb*2+(quad>>1), phys = slot^(q15&7)
      int phys = (cb * 2 + (quad >> 1)) ^ (q15 & 7);
      *(uint2*)&Prow[phys * 8 + (quad & 1) * 4] = pw;
    }

    // PV (swapped: A=V^T, B=P): out[d][i] += sum_j V^T[d][j] P[i][j]
    __builtin_amdgcn_s_setprio(1);
    #pragma unroll
    for (int ks = 0; ks < 2; ++ks) {
      // j-slice ks*32+quad*8..+7 -> slot ks*4+quad, phys = slot^(q15&7)
      bf16x8 ap = *(const bf16x8*)&Prow[(((ks * 4 + quad) ^ (q15 & 7))) * 8];
      #pragma unroll
      for (int db = 0; db < 4; ++db) {
        bf16x8 bv = read_swz(Vb, db * 16 + q15, ks * 4 + quad);
        o[db] = __builtin_amdgcn_mfma_f32_16x16x32_bf16(bv, ap, o[db], 0, 0, 0);
      }
    }
    __builtin_amdgcn_s_setprio(0);
  }

  // reduce l across the 4 quads holding the same i
  l_acc += __shfl_xor(l_acc, 16, 64);
  l_acc += __shfl_xor(l_acc, 32, 64);

  __syncthreads();  // all T reads done — tx region reusable as exchange

  if (w >= 4) {  // B-half: pass o + l to A-half
    const int ww = w - 4;
    #pragma unroll
    for (int db = 0; db < 4; ++db)
      #pragma unroll
      for (int r = 0; r < 4; ++r)
        tx.bnc[ww][db * 16 + quad * 4 + r][q15] = o[db][r];
    tx.bnc[ww][64][q15] = l_acc;  // 4 quads write same value (benign)
  }
  __syncthreads();
  if (w < 4) {
    float lB = tx.bnc[w][64][q15];
    float inv = 1.f / (l_acc + lB + 1e-30f);
    // combined, scaled, bf16-packed into transpose bounce Bt[16 i][72 d]
    unsigned short* Bt = (unsigned short*)&Kbuf[0][0] + (size_t)w * 16 * 72;
    #pragma unroll
    for (int db = 0; db < 4; ++db) {
      float v0 = (o[db][0] + tx.bnc[w][db * 16 + quad * 4 + 0][q15]) * inv;
      float v1 = (o[db][1] + tx.bnc[w][db * 16 + quad * 4 + 1][q15]) * inv;
      float v2 = (o[db][2] + tx.bnc[w][db * 16 + quad * 4 + 2][q15]) * inv;
      float v3 = (o[db][3] + tx.bnc[w][db * 16 + quad * 4 + 3][q15]) * inv;
      uint2 bw;
      bw.x = (unsigned)bfc(v0) | ((unsigned)bfc(v1) << 16);
      bw.y = (unsigned)bfc(v2) | ((unsigned)bfc(v3) << 16);
      *(uint2*)&Bt[q15 * 72 + db * 16 + quad * 4] = bw;
    }
    // read back row-major and store coalesced: lane -> row i=lane>>2,
    // d-chunk (lane&3)*16
    const int il = lane >> 2, ch = (lane & 3) * 16;
    bf16x8 u0 = *(const bf16x8*)&Bt[il * 72 + ch];
    bf16x8 u1 = *(const bf16x8*)&Bt[il * 72 + ch + 8];
    const int b = bh >> 4, h = bh & 15;
    size_t addr = ((size_t)(b * 1024 + blockIdx.y * 64 + w * 16 + il)) * 1024
                + h * 64 + ch;
    *(bf16x8*)&ao[addr] = u0;
    *(bf16x8*)&ao[addr + 8] = u1;
  }
}

// ---------------- GEMM out = ao @ WoT^T + bo — 64x64 tiles, BK=128 ---------
// R11-proven: lo/hi sub-tiles, barriers halved, 512-block grid.
__global__ __launch_bounds__(256)
void gemm_out(const unsigned short* __restrict__ A,
              const unsigned short* __restrict__ Bt,
              const unsigned short* __restrict__ bias,
              float* __restrict__ fo) {
  __shared__ __align__(16) unsigned short As2[2][64 * 64];
  __shared__ __align__(16) unsigned short Bs2[2][64 * 64];
  const int tid  = threadIdx.x;
  const int lane = tid & 63, w = tid >> 6;
  const int q15  = lane & 15, quad = lane >> 4;
  const int m0 = blockIdx.y * 64, n0 = blockIdx.x * 64;
  const int K = 1024, N = 1024;

  f32x4 acc[4] = {};
  for (int k0 = 0; k0 < K; k0 += 128) {
    __syncthreads();
    stage16(&A[(size_t)m0 * K + k0], K, As2[0], w * 16, lane);
    stage16(&A[(size_t)m0 * K + k0 + 64], K, As2[1], w * 16, lane);
    stage16(&Bt[(size_t)n0 * K + k0], K, Bs2[0], w * 16, lane);
    stage16(&Bt[(size_t)n0 * K + k0 + 64], K, Bs2[1], w * 16, lane);
    __syncthreads();
    #pragma unroll
    for (int ks = 0; ks < 4; ++ks) {
      const int hf = ks >> 1, kk = ks & 1;
      bf16x8 af = read_swz(As2[hf], w * 16 + q15, kk * 4 + quad);
      bf16x8 bfr[4];
      #pragma unroll
      for (int j = 0; j < 4; ++j)
        bfr[j] = read_swz(Bs2[hf], j * 16 + q15, kk * 4 + quad);
      #pragma unroll
      for (int j = 0; j < 4; ++j)
        acc[j] = __builtin_amdgcn_mfma_f32_16x16x32_bf16(af, bfr[j], acc[j], 0, 0, 0);
    }
  }
  #pragma unroll
  for (int j = 0; j < 4; ++j)
    #pragma unroll
    for (int r = 0; r < 4; ++r) {
      int row = m0 + w * 16 + quad * 4 + r;
      int col = n0 + j * 16 + q15;
      fo[(size_t)row * N + col] = acc[j][r] + bf2f(bias[col]);
    }
}

// ---------------------------------------------------------------------------
extern "C" void kernel_launch(void* const* d_in, const int* in_sizes, int n_in,
                              void* d_out, int out_size, void* d_ws, size_t ws_size,
                              hipStream_t stream) {
  (void)in_sizes; (void)n_in; (void)out_size; (void)ws_size;
  const float* x   = (const float*)d_in[0];
  const float* Wq  = (const float*)d_in[1];
  const float* Wkv = (const float*)d_in[2];
  const float* Wo  = (const float*)d_in[3];
  const float* bo  = (const float*)d_in[4];
  const float* rel = (const float*)d_in[5];
  float* out = (float*)d_out;

  unsigned short* ws = (unsigned short*)d_ws;
  unsigned short* WoT   = ws;                      // 1,048,576
  unsigned short* relb  = WoT   + 1048576;         // 65,664 reserved
  unsigned short* bob   = relb  + 65664;           // 1,088 reserved
  unsigned short* q_ws  = bob   + 1088;            // 2,097,152
  unsigned short* k_ws  = q_ws  + 2097152;         // 2,097,152
  unsigned short* vT    = k_ws  + 2097152;         // 2,097,152
  unsigned short* WqkvT = vT    + 2097152;         // 3,145,728 (dead after gemm_qkv)
  unsigned short* xb    = WqkvT + 3145728;         // 2,097,152 (dead after gemm_qkv)
  unsigned short* ao    = WqkvT;                   // alias

  prep_k<<<6210, 256, 0, stream>>>(x, rel, bo, Wq, Wkv, Wo,
                                   xb, relb, bob, WqkvT, WoT);
  gemm_qkv<<<dim3(24, 32), 256, 0, stream>>>(xb, WqkvT, q_ws, k_ws, vT);
  flash_attn<<<dim3(32, 16), 512, 0, stream>>>(q_ws, k_ws, vT, relb, ao);
  gemm_out<<<dim3(16, 32), 256, 0, stream>>>(ao, WoT, bob, out);
}

// Round 14
// 154.409 us; speedup vs baseline: 1.0141x; 1.0141x over previous
//
#include <hip/hip_runtime.h>

typedef __bf16 bf16x8 __attribute__((ext_vector_type(8)));
typedef float f32x4 __attribute__((ext_vector_type(4)));

#define DEV __device__ __forceinline__

DEV unsigned short f2bf(float f) {
  union { float f; unsigned u; } x; x.f = f;
  unsigned r = x.u + 0x7FFFu + ((x.u >> 16) & 1u);  // RNE
  return (unsigned short)(r >> 16);
}
DEV float bf2f(unsigned short h) {
  union { unsigned u; float f; } x; x.u = ((unsigned)h) << 16;
  return x.f;
}
DEV unsigned short bfc(float f) {  // hw cvt (RNE)
  union { __bf16 b; unsigned short u; } c; c.b = (__bf16)f; return c.u;
}

typedef __attribute__((address_space(3))) void* lds_vp;
typedef const __attribute__((address_space(1))) void* gbl_vp;
DEV void load_lds16(const unsigned short* gp, void* lp) {
  __builtin_amdgcn_global_load_lds((gbl_vp)(const void*)gp, (lds_vp)lp, 16, 0, 0);
}

// ---- fused ingest (inputs f32): convert x/rel/bo, transpose Wq|Wkv|Wo -----
__global__ __launch_bounds__(256)
void prep_k(const float* __restrict__ x, const float* __restrict__ rel,
            const float* __restrict__ bo, const float* __restrict__ Wq,
            const float* __restrict__ Wkv, const float* __restrict__ Wo,
            unsigned short* __restrict__ xb, unsigned short* __restrict__ relb,
            unsigned short* __restrict__ bob, unsigned short* __restrict__ WqkvT,
            unsigned short* __restrict__ WoT) {
  __shared__ unsigned short tile[32][33];
  const int bid = blockIdx.x, tid = threadIdx.x;
  if (bid < 2114) {
    const float* src; unsigned short* dst; long base; long n;
    if (bid < 2048)      { src = x;   dst = xb;   base = (long)bid * 1024;          n = 2097152; }
    else if (bid < 2113) { src = rel; dst = relb; base = (long)(bid - 2048) * 1024; n = 65600; }
    else                 { src = bo;  dst = bob;  base = 0;                          n = 1024; }
    long i = base + tid * 4;
    if (i < n) {
      float4 v = *(const float4*)&src[i];
      unsigned long long u = (unsigned long long)f2bf(v.x)
                           | ((unsigned long long)f2bf(v.y) << 16)
                           | ((unsigned long long)f2bf(v.z) << 32)
                           | ((unsigned long long)f2bf(v.w) << 48);
      *(unsigned long long*)&dst[i] = u;
    }
  } else {
    int id = bid - 2114;
    const float* src; unsigned short* dst; const int R = 1024; int C, txt, tyt;
    if (id < 1024)      { src = Wq;  dst = WqkvT;           C = 1024; txt = id & 31; tyt = id >> 5; }
    else if (id < 3072) { int l = id - 1024; src = Wkv; dst = WqkvT + 1048576; C = 2048; txt = l & 63; tyt = l >> 6; }
    else                { int l = id - 3072; src = Wo;  dst = WoT;             C = 1024; txt = l & 31; tyt = l >> 5; }
    int c0 = txt * 32, r0 = tyt * 32;
    int tx = tid & 31, ty = tid >> 5;
    #pragma unroll
    for (int i = 0; i < 4; ++i)
      tile[ty + i * 8][tx] = f2bf(src[(size_t)(r0 + ty + i * 8) * C + c0 + tx]);
    __syncthreads();
    #pragma unroll
    for (int i = 0; i < 4; ++i)
      dst[(size_t)(c0 + ty + i * 8) * R + r0 + tx] = tile[tx][ty + i * 8];
  }
}

// ---- XOR-8 swizzled staging/read for 64-short-row LDS tiles ---------------
DEV void stage16(const unsigned short* gbase, size_t gstride,
                 unsigned short* lbase, int r0, int lane) {
  #pragma unroll
  for (int t = 0; t < 2; ++t) {
    int r = r0 + t * 8 + (lane >> 3);
    int lc = (lane & 7) ^ (r & 7);
    load_lds16(&gbase[(size_t)r * gstride + lc * 8], &lbase[(size_t)(r0 + t * 8) * 64]);
  }
}
DEV bf16x8 read_swz(const unsigned short* buf, int row, int lc) {
  int pc = lc ^ (row & 7);
  return *(const bf16x8*)&buf[row * 64 + pc * 8];
}

// ---------------- GEMM qkv = x @ WqkvT^T — 64x128 tiles, BK=128 ------------
// R11-proven: lo/hi K-halves, barriers halved, 768 blocks = 3/CU balanced.
__global__ __launch_bounds__(256)
void gemm_qkv(const unsigned short* __restrict__ A,
              const unsigned short* __restrict__ Bt,
              unsigned short* __restrict__ o0,   // q [b,h,n,d] *0.125
              unsigned short* __restrict__ o1,   // k [b,h,n,d]
              unsigned short* __restrict__ o2) { // vT [b,h,d,n]
  union UA {
    unsigned short As2[2][64 * 64];   // lo/hi K-halves
    unsigned short tb[64][68];        // epilogue only (A dead then)
  };
  __shared__ __align__(16) UA u;
  __shared__ __align__(16) unsigned short Bs2[2][128 * 64];
  const int tid  = threadIdx.x;
  const int lane = tid & 63, wave = tid >> 6;
  const int q15  = lane & 15, quad = lane >> 4;
  const int wr = wave >> 1, wc = wave & 1;
  const int m0 = blockIdx.y * 64, n0 = blockIdx.x * 128;
  const int K = 1024;

  f32x4 acc[2][4] = {};
  for (int k0 = 0; k0 < K; k0 += 128) {
    __syncthreads();
    stage16(&A[(size_t)m0 * K + k0], K, u.As2[0], wave * 16, lane);
    stage16(&A[(size_t)m0 * K + k0 + 64], K, u.As2[1], wave * 16, lane);
    stage16(&Bt[(size_t)n0 * K + k0], K, Bs2[0], wave * 32, lane);
    stage16(&Bt[(size_t)n0 * K + k0], K, Bs2[0], wave * 32 + 16, lane);
    stage16(&Bt[(size_t)n0 * K + k0 + 64], K, Bs2[1], wave * 32, lane);
    stage16(&Bt[(size_t)n0 * K + k0 + 64], K, Bs2[1], wave * 32 + 16, lane);
    __syncthreads();
    #pragma unroll
    for (int ks = 0; ks < 4; ++ks) {
      const int hf = ks >> 1, kk = ks & 1;
      bf16x8 af[2], bfr[4];
      #pragma unroll
      for (int i = 0; i < 2; ++i)
        af[i] = read_swz(u.As2[hf], wr * 32 + i * 16 + q15, kk * 4 + quad);
      #pragma unroll
      for (int j = 0; j < 4; ++j)
        bfr[j] = read_swz(Bs2[hf], wc * 64 + j * 16 + q15, kk * 4 + quad);
      #pragma unroll
      for (int i = 0; i < 2; ++i)
        #pragma unroll
        for (int j = 0; j < 4; ++j)
          acc[i][j] = __builtin_amdgcn_mfma_f32_16x16x32_bf16(af[i], bfr[j], acc[i][j], 0, 0, 0);
    }
  }

  const int b = m0 >> 10, nn0 = m0 & 1023;
  if (n0 < 2048) {
    #pragma unroll
    for (int i = 0; i < 2; ++i)
      #pragma unroll
      for (int j = 0; j < 4; ++j)
        #pragma unroll
        for (int r = 0; r < 4; ++r) {
          int row = m0 + wr * 32 + i * 16 + quad * 4 + r;
          int col = n0 + wc * 64 + j * 16 + q15;
          float v = acc[i][j][r];
          int nn = row & 1023;
          unsigned short* dst; int c = col; float sc = 1.f;
          if (col < 1024) { dst = o0; sc = 0.125f; }
          else            { dst = o1; c = col - 1024; }
          int h = c >> 6, dd = c & 63;
          dst[((size_t)((row >> 10) * 16 + h) * 1024 + nn) * 64 + dd] = f2bf(v * sc);
        }
  } else {
    const int hp = (n0 - 2048) >> 6;
    #pragma unroll
    for (int hh = 0; hh < 2; ++hh) {
      __syncthreads();
      if (wc == hh) {
        #pragma unroll
        for (int i = 0; i < 2; ++i)
          #pragma unroll
          for (int j = 0; j < 4; ++j)
            #pragma unroll
            for (int r = 0; r < 4; ++r)
              u.tb[wr * 32 + i * 16 + quad * 4 + r][j * 16 + q15] = f2bf(acc[i][j][r]);
      }
      __syncthreads();
      const int bh = b * 16 + hp + hh;
      const int d = tid >> 2, nb = (tid & 3) * 16;
      #pragma unroll
      for (int s = 0; s < 2; ++s) {
        int n = nb + s * 8;
        union { uint4 v; unsigned short us[8]; } t;
        #pragma unroll
        for (int e = 0; e < 8; ++e) t.us[e] = u.tb[n + e][d];
        *(uint4*)&o2[((size_t)bh * 64 + d) * 1024 + nn0 + n] = t.v;
      }
    }
  }
}

// ---------------- flash attention: SWAPPED operands, 8-wave j-split --------
// R8-exact inner loop (best measured 52.4 us). R12's jt-skew REVERTED: the
// co-resident block pair (y, y+8) shares bh -> same K/V tiles; phase-locked
// staging hits L2, skew broke that (-3.6 us). Frozen.
__global__ __launch_bounds__(512)
void flash_attn(const unsigned short* __restrict__ q_ws,   // pre-scaled .125
                const unsigned short* __restrict__ k_ws,
                const unsigned short* __restrict__ vt_ws,  // [bh][64][1024]
                const unsigned short* __restrict__ rel,    // [1025][64]
                unsigned short* __restrict__ ao) {         // [2048][1024]
  __shared__ __align__(16) unsigned short Kbuf[2][64 * 64];   // [j-half]
  __shared__ __align__(16) unsigned short Vbuf[2][64 * 64];   // [j-half]
  __shared__ __align__(16) unsigned short P_lds[8][16 * 64];  // XOR-8 16B slots
  union TXu {
    unsigned short T[8][16][84];  // bf16 band, rows = i, cols = band-c
    float bnc[4][65][17];         // epilogue o/l exchange (B-half -> A-half)
  };
  __shared__ __align__(16) TXu tx;

  const int tid  = threadIdx.x;
  const int lane = tid & 63, w = tid >> 6;
  const int q15  = lane & 15, quad = lane >> 4;
  const int wr4  = w & 3, jh = w >> 2;
  const int bh = blockIdx.x;
  const int ib = blockIdx.y * 64 + wr4 * 16;

  const unsigned short* qp = q_ws  + (size_t)bh * 1024 * 64;
  const unsigned short* kp = k_ws  + (size_t)bh * 1024 * 64;
  const unsigned short* tp = vt_ws + (size_t)bh * 64 * 1024;

  unsigned short* Kb = &Kbuf[jh][0];
  unsigned short* Vb = &Vbuf[jh][0];
  unsigned short* Trow = &tx.T[w][q15][0];          // this lane's i-row band
  unsigned short* Prow = &P_lds[w][q15 * 64];       // this lane's i-row P

  bf16x8 aq[2];
  #pragma unroll
  for (int ks = 0; ks < 2; ++ks)
    aq[ks] = *(const bf16x8*)&qp[(size_t)(ib + q15) * 64 + ks * 32 + quad * 8];

  f32x4 o[4] = {};          // o[db][r]: out[d = db*16+quad*4+r][i = q15]
  float l_acc = 0.f;        // row-sum for i = ib + q15 (partial over quads)

  for (int jt = 0; jt < 8; ++jt) {
    const int j0 = jh * 512 + jt * 64;
    __syncthreads();  // prev-iter K/V reads done; buffers free
    stage16(kp + (size_t)j0 * 64, 64, Kb, wr4 * 16, lane);
    stage16(tp + j0, 1024, Vb, wr4 * 16, lane);

    // T-phase (swapped: A=rel, B=q): out[trow-row][i-col]. Independent of
    // K/V buffers — overlaps staging latency.
    int tb = ib - j0 + 512 - 63;
    f32x4 accT[5] = {};
    __builtin_amdgcn_s_setprio(1);
    #pragma unroll
    for (int ks = 0; ks < 2; ++ks)
      #pragma unroll
      for (int ub = 0; ub < 5; ++ub) {
        int trow = tb + ub * 16 + q15;
        trow = trow < 0 ? 0 : (trow > 1024 ? 1024 : trow);
        bf16x8 br = *(const bf16x8*)&rel[(size_t)trow * 64 + ks * 32 + quad * 8];
        accT[ub] = __builtin_amdgcn_mfma_f32_16x16x32_bf16(br, aq[ks], accT[ub], 0, 0, 0);
      }
    __builtin_amdgcn_s_setprio(0);
    // lane holds T[trow = tb+ub*16+quad*4+r][i=q15] -> store T[i][c],
    // c = ub*16+quad*4+r: 4 contiguous per ub -> packed b64 writes.
    #pragma unroll
    for (int ub = 0; ub < 5; ++ub) {
      uint2 tw;
      tw.x = (unsigned)bfc(accT[ub][0]) | ((unsigned)bfc(accT[ub][1]) << 16);
      tw.y = (unsigned)bfc(accT[ub][2]) | ((unsigned)bfc(accT[ub][3]) << 16);
      *(uint2*)&Trow[ub * 16 + quad * 4] = tw;
    }

    __syncthreads();  // staging landed (vmcnt drained before barrier)

    // S' = mfma(A=K, B=Q): lane holds S[j = j0+cb*16+quad*4+r][i = ib+q15]
    f32x4 accS[4] = {};
    __builtin_amdgcn_s_setprio(1);
    #pragma unroll
    for (int ks = 0; ks < 2; ++ks)
      #pragma unroll
      for (int cb = 0; cb < 4; ++cb) {
        bf16x8 bk = read_swz(Kb, cb * 16 + q15, ks * 4 + quad);
        accS[cb] = __builtin_amdgcn_mfma_f32_16x16x32_bf16(bk, aq[ks], accS[cb], 0, 0, 0);
      }
    __builtin_amdgcn_s_setprio(0);

    // softmax: i fixed per lane; T gather is T[i][63 + q15 - j_local]
    #pragma unroll
    for (int cb = 0; cb < 4; ++cb) {
      float p[4];
      #pragma unroll
      for (int r = 0; r < 4; ++r) {
        int jl = cb * 16 + quad * 4 + r;
        float s = accS[cb][r] + bf2f(Trow[63 + q15 - jl]);
        p[r] = exp2f(fmaf(s, 1.44269504f, -64.f));
        l_acc += p[r];
      }
      uint2 pw;
      pw.x = (unsigned)bfc(p[0]) | ((unsigned)bfc(p[1]) << 16);
      pw.y = (unsigned)bfc(p[2]) | ((unsigned)bfc(p[3]) << 16);
      // j = cb*16+quad*4+r; 16B slot = cb*2+(quad>>1), phys = slot^(q15&7)
      int phys = (cb * 2 + (quad >> 1)) ^ (q15 & 7);
      *(uint2*)&Prow[phys * 8 + (quad & 1) * 4] = pw;
    }

    // PV (swapped: A=V^T, B=P): out[d][i] += sum_j V^T[d][j] P[i][j]
    __builtin_amdgcn_s_setprio(1);
    #pragma unroll
    for (int ks = 0; ks < 2; ++ks) {
      // j-slice ks*32+quad*8..+7 -> slot ks*4+quad, phys = slot^(q15&7)
      bf16x8 ap = *(const bf16x8*)&Prow[(((ks * 4 + quad) ^ (q15 & 7))) * 8];
      #pragma unroll
      for (int db = 0; db < 4; ++db) {
        bf16x8 bv = read_swz(Vb, db * 16 + q15, ks * 4 + quad);
        o[db] = __builtin_amdgcn_mfma_f32_16x16x32_bf16(bv, ap, o[db], 0, 0, 0);
      }
    }
    __builtin_amdgcn_s_setprio(0);
  }

  // reduce l across the 4 quads holding the same i
  l_acc += __shfl_xor(l_acc, 16, 64);
  l_acc += __shfl_xor(l_acc, 32, 64);

  __syncthreads();  // all T reads done — tx region reusable as exchange

  if (w >= 4) {  // B-half: pass o + l to A-half
    const int ww = w - 4;
    #pragma unroll
    for (int db = 0; db < 4; ++db)
      #pragma unroll
      for (int r = 0; r < 4; ++r)
        tx.bnc[ww][db * 16 + quad * 4 + r][q15] = o[db][r];
    tx.bnc[ww][64][q15] = l_acc;  // 4 quads write same value (benign)
  }
  __syncthreads();
  if (w < 4) {
    float lB = tx.bnc[w][64][q15];
    float inv = 1.f / (l_acc + lB + 1e-30f);
    // combined, scaled, bf16-packed into transpose bounce Bt[16 i][72 d]
    unsigned short* Bt = (unsigned short*)&Kbuf[0][0] + (size_t)w * 16 * 72;
    #pragma unroll
    for (int db = 0; db < 4; ++db) {
      float v0 = (o[db][0] + tx.bnc[w][db * 16 + quad * 4 + 0][q15]) * inv;
      float v1 = (o[db][1] + tx.bnc[w][db * 16 + quad * 4 + 1][q15]) * inv;
      float v2 = (o[db][2] + tx.bnc[w][db * 16 + quad * 4 + 2][q15]) * inv;
      float v3 = (o[db][3] + tx.bnc[w][db * 16 + quad * 4 + 3][q15]) * inv;
      uint2 bw;
      bw.x = (unsigned)bfc(v0) | ((unsigned)bfc(v1) << 16);
      bw.y = (unsigned)bfc(v2) | ((unsigned)bfc(v3) << 16);
      *(uint2*)&Bt[q15 * 72 + db * 16 + quad * 4] = bw;
    }
    // read back row-major and store coalesced: lane -> row i=lane>>2,
    // d-chunk (lane&3)*16
    const int il = lane >> 2, ch = (lane & 3) * 16;
    bf16x8 u0 = *(const bf16x8*)&Bt[il * 72 + ch];
    bf16x8 u1 = *(const bf16x8*)&Bt[il * 72 + ch + 8];
    const int b = bh >> 4, h = bh & 15;
    size_t addr = ((size_t)(b * 1024 + blockIdx.y * 64 + w * 16 + il)) * 1024
                + h * 64 + ch;
    *(bf16x8*)&ao[addr] = u0;
    *(bf16x8*)&ao[addr + 8] = u1;
  }
}

// ---------------- GEMM out = ao @ WoT^T + bo — 64x64 tiles, BK=128 ---------
// R11-proven: lo/hi sub-tiles, barriers halved, 512-block grid.
__global__ __launch_bounds__(256)
void gemm_out(const unsigned short* __restrict__ A,
              const unsigned short* __restrict__ Bt,
              const unsigned short* __restrict__ bias,
              float* __restrict__ fo) {
  __shared__ __align__(16) unsigned short As2[2][64 * 64];
  __shared__ __align__(16) unsigned short Bs2[2][64 * 64];
  const int tid  = threadIdx.x;
  const int lane = tid & 63, w = tid >> 6;
  const int q15  = lane & 15, quad = lane >> 4;
  const int m0 = blockIdx.y * 64, n0 = blockIdx.x * 64;
  const int K = 1024, N = 1024;

  f32x4 acc[4] = {};
  for (int k0 = 0; k0 < K; k0 += 128) {
    __syncthreads();
    stage16(&A[(size_t)m0 * K + k0], K, As2[0], w * 16, lane);
    stage16(&A[(size_t)m0 * K + k0 + 64], K, As2[1], w * 16, lane);
    stage16(&Bt[(size_t)n0 * K + k0], K, Bs2[0], w * 16, lane);
    stage16(&Bt[(size_t)n0 * K + k0 + 64], K, Bs2[1], w * 16, lane);
    __syncthreads();
    #pragma unroll
    for (int ks = 0; ks < 4; ++ks) {
      const int hf = ks >> 1, kk = ks & 1;
      bf16x8 af = read_swz(As2[hf], w * 16 + q15, kk * 4 + quad);
      bf16x8 bfr[4];
      #pragma unroll
      for (int j = 0; j < 4; ++j)
        bfr[j] = read_swz(Bs2[hf], j * 16 + q15, kk * 4 + quad);
      #pragma unroll
      for (int j = 0; j < 4; ++j)
        acc[j] = __builtin_amdgcn_mfma_f32_16x16x32_bf16(af, bfr[j], acc[j], 0, 0, 0);
    }
  }
  #pragma unroll
  for (int j = 0; j < 4; ++j)
    #pragma unroll
    for (int r = 0; r < 4; ++r) {
      int row = m0 + w * 16 + quad * 4 + r;
      int col = n0 + j * 16 + q15;
      fo[(size_t)row * N + col] = acc[j][r] + bf2f(bias[col]);
    }
}

// ---------------------------------------------------------------------------
extern "C" void kernel_launch(void* const* d_in, const int* in_sizes, int n_in,
                              void* d_out, int out_size, void* d_ws, size_t ws_size,
                              hipStream_t stream) {
  (void)in_sizes; (void)n_in; (void)out_size; (void)ws_size;
  const float* x   = (const float*)d_in[0];
  const float* Wq  = (const float*)d_in[1];
  const float* Wkv = (const float*)d_in[2];
  const float* Wo  = (const float*)d_in[3];
  const float* bo  = (const float*)d_in[4];
  const float* rel = (const float*)d_in[5];
  float* out = (float*)d_out;

  unsigned short* ws = (unsigned short*)d_ws;
  unsigned short* WoT   = ws;                      // 1,048,576
  unsigned short* relb  = WoT   + 1048576;         // 65,664 reserved
  unsigned short* bob   = relb  + 65664;           // 1,088 reserved
  unsigned short* q_ws  = bob   + 1088;            // 2,097,152
  unsigned short* k_ws  = q_ws  + 2097152;         // 2,097,152
  unsigned short* vT    = k_ws  + 2097152;         // 2,097,152
  unsigned short* WqkvT = vT    + 2097152;         // 3,145,728 (dead after gemm_qkv)
  unsigned short* xb    = WqkvT + 3145728;         // 2,097,152 (dead after gemm_qkv)
  unsigned short* ao    = WqkvT;                   // alias

  prep_k<<<6210, 256, 0, stream>>>(x, rel, bo, Wq, Wkv, Wo,
                                   xb, relb, bob, WqkvT, WoT);
  gemm_qkv<<<dim3(24, 32), 256, 0, stream>>>(xb, WqkvT, q_ws, k_ws, vT);
  flash_attn<<<dim3(32, 16), 512, 0, stream>>>(q_ws, k_ws, vT, relb, ao);
  gemm_out<<<dim3(16, 32), 256, 0, stream>>>(ao, WoT, bob, out);
}